// Round 15
// baseline (837.354 us; speedup 1.0000x reference)
//
#include <hip/hip_runtime.h>

#define NPTS 4096
#define CH 64
#define BATCH 8
#define KNN 20
#define NEG_SLOPE 0.2f
#define EPSV 1e-5f
#define NEG_INF (-3.4e38f)

typedef float v2f __attribute__((ext_vector_type(2)));

// ---------------- K2: P'[t,o], Q'[t,o], and xx (fused) ----------------
__global__ void k_pq(const float* __restrict__ x, const float* __restrict__ W,
                     const float* __restrict__ gamma, const float* __restrict__ beta,
                     const float* __restrict__ rmean, const float* __restrict__ rvar,
                     float* __restrict__ P, float* __restrict__ Q,
                     float* __restrict__ xx) {
  __shared__ float Ws1[CH * CH];   // [c][o], W1*inv
  __shared__ float Wsd[CH * CH];   // [c][o], (W2-W1)*inv
  int tid = threadIdx.x;
  for (int i = tid; i < CH * CH; i += 256) {
    int o = i & 63, c = i >> 6;
    float s = gamma[o] * rsqrtf(rvar[o] + EPSV);
    float w1 = W[o * 128 + c], w2 = W[o * 128 + 64 + c];
    Ws1[c * 64 + o] = w1 * s;
    Wsd[c * 64 + o] = (w2 - w1) * s;
  }
  __syncthreads();
  int o = tid & 63, ng = tid >> 6;
  float s = gamma[o] * rsqrtf(rvar[o] + EPSV);
  float shift = beta[o] - rmean[o] * s;
  int base = blockIdx.x * 16;
  for (int rp = 0; rp < 4; ++rp) {
    int t = base + rp * 4 + ng;                    // row in [0, B*N)
    int b = t >> 12, n = t & (NPTS - 1);
    const float* xp = x + ((size_t)b * CH * NPTS) + n;
    float accp = 0.f, accq = 0.f, accx = 0.f;
#pragma unroll 8
    for (int c = 0; c < CH; ++c) {
      float xv = xp[(size_t)c * NPTS];
      accp = fmaf(xv, Ws1[c * 64 + o], accp);
      accq = fmaf(xv, Wsd[c * 64 + o], accq);
      accx = fmaf(xv, xv, accx);                   // same chain as old k_xx
    }
    P[(size_t)t * 64 + o] = accp;
    Q[(size_t)t * 64 + o] = accq + shift;
    if (o == 0) xx[t] = accx;
  }
}

// ---------------- K1 helpers ----------------
// forced v_pk_fma_f32 (R14, passed): two output rows per A-pair via op_sel
// broadcast. Each lane is an IEEE fma -> bit-identical chains.
__device__ __forceinline__ void fma2pair(v2f ap, v2f b, v2f& aclo, v2f& achi) {
  asm("v_pk_fma_f32 %0, %1, %2, %0 op_sel:[0,0,0] op_sel_hi:[0,1,1]"
      : "+v"(aclo) : "v"(ap), "v"(b));
  asm("v_pk_fma_f32 %0, %1, %2, %0 op_sel:[1,0,0] op_sel_hi:[1,1,1]"
      : "+v"(achi) : "v"(ap), "v"(b));
}

// strict total order: (d desc, col asc). Reproduces the serial path's
// "existing equals stay above" because list cols are always < group cols.
__device__ __forceinline__ bool kgreater(float v1, int i1, float v2, int i2) {
  return (v1 > v2) || (v1 == v2 && i1 < i2);
}

// full 64-lane bitonic sort, desc by kgreater (R5's trusted seed network).
__device__ __forceinline__ void sort64(float& v, int& ix, int lane) {
#pragma unroll
  for (int k = 2; k <= 64; k <<= 1) {
#pragma unroll
    for (int j = k >> 1; j > 0; j >>= 1) {
      float pv = __shfl_xor(v, j);
      int   pi = __shfl_xor(ix, j);
      bool lower = (lane & j) == 0;
      bool desc  = (lane & k) == 0;
      bool mineBefore = kgreater(v, ix, pv, pi);
      bool keep = (mineBefore == (lower == desc));
      v  = keep ? v  : pv;
      ix = keep ? ix : pi;
    }
  }
}

// merge sorted-desc group (v,ix) into sorted-desc list (vr,ir), keep top-64:
// half-cleaner C[l] = max(list[l], group[63-l]) (bitonic) + 6-stage cleanup.
// Exactly the top-64 of the union under kgreater -> top-20 identical to the
// serial-insert path (entries below rank 19 never rise; th = lane 19).
__device__ __forceinline__ void merge64(float v, int ix, int lane,
                                        float& vr, int& ir, float& th) {
  float bv = __shfl(v, 63 - lane);
  int   bi = __shfl(ix, 63 - lane);
  bool takeB = kgreater(bv, bi, vr, ir);
  float nv = takeB ? bv : vr;
  int   ni = takeB ? bi : ir;
#pragma unroll
  for (int j = 32; j > 0; j >>= 1) {
    float pv = __shfl_xor(nv, j);
    int   pi = __shfl_xor(ni, j);
    bool lower = (lane & j) == 0;
    bool mineBefore = kgreater(nv, ni, pv, pi);
    bool keep = (mineBefore == lower);
    nv = keep ? nv : pv;
    ni = keep ? ni : pi;
  }
  vr = nv; ir = ni; th = __shfl(nv, KNN - 1);
}

// ballot-gated serial insert with threshold tightening (R5-R14, passed).
// List stays fully sorted, so km is a prefix count -> correct position.
__device__ __forceinline__ void insert_serial(float d, unsigned long long hit,
                                              int mg, int lane,
                                              float& vr, int& ir, float& th) {
  while (hit) {
    int j = __builtin_ctzll(hit);
    hit &= hit - 1;
    float cv = __shfl(d, j);
    int cm = mg + j;
    unsigned long long km = __ballot(vr >= cv);    // existing equals stay above
    int cnt = __popcll(km);
    float sv = __shfl_up(vr, 1);
    int si = __shfl_up(ir, 1);
    if (lane >= cnt) {
      vr = (lane == cnt) ? cv : sv;
      ir = (lane == cnt) ? cm : si;
    }
    th = __shfl(vr, KNN - 1);
    if (hit) hit &= __ballot(d > th);              // prune sub-threshold hits
  }
}

// hybrid group processor: dense -> log-depth sort+merge; sparse -> serial.
// Both paths produce the identical sorted top-64 -> identical top-20.
__device__ __forceinline__ void do_group(float d, int mg, int lane,
                                         float& vr, int& ir, float& th) {
  unsigned long long hit = __ballot(d > th);
  if (hit == 0ull) return;
  if (__popcll(hit) >= 8) {
    float v = d; int ix = mg + lane;
    sort64(v, ix, lane);
    merge64(v, ix, lane, vr, ir, th);
  } else {
    insert_serial(d, hit, mg, lane, vr, ir, th);
  }
}

// GEMM (8 rows x 8 cols per thread; lane==col within each 64-group) +
// register-direct hybrid selection. R14 chassis (pk-fma, B from L2, one
// barrier). Candidate order: chunks ascending, groups g=0..7 ascending ->
// top-20 per row identical to all prior passing rounds.
template <bool SEED>
__device__ __forceinline__ void tile_work(const float* __restrict__ bp,
                                          const float* As,
                                          const float* xxb, int m0, int w, int lane,
                                          const float (&xnr)[8],
                                          float (&val)[8], int (&idx)[8],
                                          float (&thd)[8]) {
  float xm[8];
#pragma unroll
  for (int g = 0; g < 8; ++g) xm[g] = xxb[m0 + 64 * g + lane];

  const float* Aw = As + 8 * w;                    // rows 8w..8w+7, LDA=64
  const float* bc = bp + m0;                       // per-lane: col m0+lane

  v2f acc[8][4];                                   // [row][col-pair]
#pragma unroll
  for (int r = 0; r < 8; ++r)
#pragma unroll
    for (int gp = 0; gp < 4; ++gp) { acc[r][gp].x = 0.f; acc[r][gp].y = 0.f; }

#pragma unroll 2
  for (int c = 0; c < CH; ++c) {
    float4 A0 = *(const float4*)(Aw + c * 64);       // rows 8w..8w+3 (broadcast)
    float4 A1 = *(const float4*)(Aw + c * 64 + 4);   // rows 8w+4..8w+7
    const float* bcc = bc + (size_t)c * NPTS;
    v2f bb[4];
    bb[0].x = bcc[0];    bb[0].y = bcc[64];
    bb[1].x = bcc[128];  bb[1].y = bcc[192];
    bb[2].x = bcc[256];  bb[2].y = bcc[320];
    bb[3].x = bcc[384];  bb[3].y = bcc[448];
    v2f a01; a01.x = A0.x; a01.y = A0.y;
    v2f a23; a23.x = A0.z; a23.y = A0.w;
    v2f a45; a45.x = A1.x; a45.y = A1.y;
    v2f a67; a67.x = A1.z; a67.y = A1.w;
#pragma unroll
    for (int gp = 0; gp < 4; ++gp) {
      fma2pair(a01, bb[gp], acc[0][gp], acc[1][gp]);
      fma2pair(a23, bb[gp], acc[2][gp], acc[3][gp]);
      fma2pair(a45, bb[gp], acc[4][gp], acc[5][gp]);
      fma2pair(a67, bb[gp], acc[6][gp], acc[7][gp]);
    }
  }

#pragma unroll
  for (int r = 0; r < 8; ++r) {
#pragma unroll
    for (int gp = 0; gp < 4; ++gp) {
      float d0 = (2.f * acc[r][gp].x - xnr[r]) - xm[2 * gp];
      int mg0 = m0 + 128 * gp;
      if constexpr (SEED) {
        if (gp == 0) {                             // chunk 0, group 0: empty
          float v = d0; int ix = lane;             //   list = sorted group
          sort64(v, ix, lane);
          val[r] = v; idx[r] = ix; thd[r] = __shfl(v, KNN - 1);
        } else {                                   // chunk 0, dense: merge
          float v = d0; int ix = mg0 + lane;
          sort64(v, ix, lane);
          merge64(v, ix, lane, val[r], idx[r], thd[r]);
        }
      } else {
        do_group(d0, mg0, lane, val[r], idx[r], thd[r]);
      }
      float d1 = (2.f * acc[r][gp].y - xnr[r]) - xm[2 * gp + 1];
      int mg1 = m0 + 128 * gp + 64;
      if constexpr (SEED) {                        // chunk 0, dense: merge
        float v = d1; int ix = mg1 + lane;
        sort64(v, ix, lane);
        merge64(v, ix, lane, val[r], idx[r], thd[r]);
      } else {
        do_group(d1, mg1, lane, val[r], idx[r], thd[r]);
      }
    }
  }
}

// ---------------- K1: fused distance-GEMM + register-direct top-20 ----------
// 512 threads = 8 waves; wave w owns rows 8w..8w+7; 64 rows/block.
// Grid = 512 blocks = 2 blocks/CU -> 16 waves/CU = 4 waves/SIMD.
// LDS = As[64][64] 16KB only; B from L2 (XCD swizzle b=bid&7); one barrier.
__launch_bounds__(512, 4)
__global__ void k_knn(const float* __restrict__ x, const float* __restrict__ xx,
                      int* __restrict__ idxout) {
  __shared__ float As[64 * 64];                    // [c][n], LDA=64
  int tid = threadIdx.x;
  int bid = blockIdx.x;
  int b = bid & 7, nb = bid >> 3;                  // XCD-swizzled decode
  int n0 = nb * 64;
  const float* xb = x + (size_t)b * CH * NPTS;
  const float* xxb = xx + b * NPTS;
  int lane = tid & 63;
  int w = tid >> 6;                                // 0..7

  // stage A-tile [c][n]: 4096 floats, 512 threads x 8 floats
  {
    int c = tid >> 3, n8 = (tid & 7) << 3;
    float4 v0 = *(const float4*)(xb + (size_t)c * NPTS + n0 + n8);
    float4 v1 = *(const float4*)(xb + (size_t)c * NPTS + n0 + n8 + 4);
    *(float4*)(As + c * 64 + n8) = v0;
    *(float4*)(As + c * 64 + n8 + 4) = v1;
  }

  float xnr[8];
#pragma unroll
  for (int r = 0; r < 8; ++r) xnr[r] = xxb[n0 + 8 * w + r];

  float val[8]; int idx[8]; float thd[8];
#pragma unroll
  for (int r = 0; r < 8; ++r) { val[r] = NEG_INF; idx[r] = 0; thd[r] = NEG_INF; }

  __syncthreads();                                 // As ready (the ONLY barrier)

  const float* bp = xb + lane;                     // per-lane B base

  // chunk 0: sort+merge seeding for all 8 groups
  tile_work<true>(bp, As, xxb, 0, w, lane, xnr, val, idx, thd);

#pragma unroll 1
  for (int mt = 1; mt < NPTS / 512; ++mt)
    tile_work<false>(bp, As, xxb, mt * 512, w, lane, xnr, val, idx, thd);

  // emit: lane l (<20) holds l-th best index for row 8w+r
#pragma unroll
  for (int r = 0; r < 8; ++r) {
    int n = n0 + 8 * w + r;
    if (lane < KNN) idxout[(size_t)(b * NPTS + n) * KNN + lane] = idx[r];
  }
}

// ---------------- K3: gather + max + leaky, transpose to (B,O,N) ----------------
__global__ void k_out(const float* __restrict__ P, const float* __restrict__ Q,
                      const int* __restrict__ idx, float* __restrict__ out) {
  __shared__ float T[64 * 65];
  int tid = threadIdx.x;
  int nb = blockIdx.x, b = blockIdx.y;
  int n0 = nb * 64;
  int o = tid & 63, ng = tid >> 6;
  const float* Pb = P + (size_t)b * NPTS * 64;
  for (int p = 0; p < 16; ++p) {
    int nl = p * 4 + ng;
    int n = n0 + nl;
    const int* ip = idx + (size_t)(b * NPTS + n) * KNN;
    float mx = NEG_INF;
#pragma unroll
    for (int k = 0; k < KNN; ++k) {
      int id = ip[k];
      float v = Pb[(size_t)id * 64 + o];
      mx = fmaxf(mx, v);
    }
    float z = mx + Q[(size_t)(b * NPTS + n) * 64 + o];
    z = (z >= 0.f) ? z : NEG_SLOPE * z;
    T[o * 65 + nl] = z;
  }
  __syncthreads();
  float* ob = out + (size_t)b * 64 * NPTS + n0;
  int nl = tid & 63;
  for (int w = 0; w < 16; ++w) {
    int oo = w * 4 + ng;
    ob[(size_t)oo * NPTS + nl] = T[oo * 65 + nl];
  }
}

extern "C" void kernel_launch(void* const* d_in, const int* in_sizes, int n_in,
                              void* d_out, int out_size, void* d_ws, size_t ws_size,
                              hipStream_t stream) {
  const float* x     = (const float*)d_in[0];
  const float* W     = (const float*)d_in[1];
  const float* gamma = (const float*)d_in[2];
  const float* beta  = (const float*)d_in[3];
  const float* rmean = (const float*)d_in[4];
  const float* rvar  = (const float*)d_in[5];
  float* out = (float*)d_out;

  float* xx = (float*)d_ws;                        // 32768 floats
  float* P  = xx + 32768;                          // 2097152 floats
  float* Q  = P + 2097152;                         // 2097152 floats
  int*   idx = (int*)(Q + 2097152);                // 655360 ints

  k_pq<<<BATCH * NPTS / 16, 256, 0, stream>>>(x, W, gamma, beta, rmean, rvar,
                                              P, Q, xx);
  k_knn<<<BATCH * NPTS / 64, 512, 0, stream>>>(x, xx, idx);
  k_out<<<dim3(NPTS / 64, BATCH), 256, 0, stream>>>(P, Q, idx, out);
}

// Round 16
// 478.100 us; speedup vs baseline: 1.7514x; 1.7514x over previous
//
#include <hip/hip_runtime.h>

#define NPTS 4096
#define CH 64
#define BATCH 8
#define KNN 20
#define NEG_SLOPE 0.2f
#define EPSV 1e-5f
#define NEG_INF (-3.4e38f)

typedef float v2f __attribute__((ext_vector_type(2)));

// ---------------- K2: P'[t,o], Q'[t,o], and xx (fused; R14, passed) --------
__global__ void k_pq(const float* __restrict__ x, const float* __restrict__ W,
                     const float* __restrict__ gamma, const float* __restrict__ beta,
                     const float* __restrict__ rmean, const float* __restrict__ rvar,
                     float* __restrict__ P, float* __restrict__ Q,
                     float* __restrict__ xx) {
  __shared__ float Ws1[CH * CH];   // [c][o], W1*inv
  __shared__ float Wsd[CH * CH];   // [c][o], (W2-W1)*inv
  int tid = threadIdx.x;
  for (int i = tid; i < CH * CH; i += 256) {
    int o = i & 63, c = i >> 6;
    float s = gamma[o] * rsqrtf(rvar[o] + EPSV);
    float w1 = W[o * 128 + c], w2 = W[o * 128 + 64 + c];
    Ws1[c * 64 + o] = w1 * s;
    Wsd[c * 64 + o] = (w2 - w1) * s;
  }
  __syncthreads();
  int o = tid & 63, ng = tid >> 6;
  float s = gamma[o] * rsqrtf(rvar[o] + EPSV);
  float shift = beta[o] - rmean[o] * s;
  int base = blockIdx.x * 16;
  for (int rp = 0; rp < 4; ++rp) {
    int t = base + rp * 4 + ng;                    // row in [0, B*N)
    int b = t >> 12, n = t & (NPTS - 1);
    const float* xp = x + ((size_t)b * CH * NPTS) + n;
    float accp = 0.f, accq = 0.f, accx = 0.f;
#pragma unroll 8
    for (int c = 0; c < CH; ++c) {
      float xv = xp[(size_t)c * NPTS];
      accp = fmaf(xv, Ws1[c * 64 + o], accp);
      accq = fmaf(xv, Wsd[c * 64 + o], accq);
      accx = fmaf(xv, xv, accx);                   // same chain as old k_xx
    }
    P[(size_t)t * 64 + o] = accp;
    Q[(size_t)t * 64 + o] = accq + shift;
    if (o == 0) xx[t] = accx;
  }
}

// ---------------- K1 helpers (all R14, passed) ----------------
// forced v_pk_fma_f32: two output rows per A-pair via op_sel broadcast.
// Each lane is an IEEE fma -> bit-identical chains.
__device__ __forceinline__ void fma2pair(v2f ap, v2f b, v2f& aclo, v2f& achi) {
  asm("v_pk_fma_f32 %0, %1, %2, %0 op_sel:[0,0,0] op_sel_hi:[0,1,1]"
      : "+v"(aclo) : "v"(ap), "v"(b));
  asm("v_pk_fma_f32 %0, %1, %2, %0 op_sel:[1,0,0] op_sel_hi:[1,1,1]"
      : "+v"(achi) : "v"(ap), "v"(b));
}

// ballot-gated serial insert with in-loop threshold tightening (R5-R14).
__device__ __forceinline__ void insert_group(float d, int mg, int lane,
                                             float& vr, int& ir, float& th) {
  unsigned long long hit = __ballot(d > th);
  while (hit) {
    int j = __builtin_ctzll(hit);
    hit &= hit - 1;
    float cv = __shfl(d, j);
    int cm = mg + j;
    unsigned long long km = __ballot(vr >= cv);    // existing equals stay above
    int cnt = __popcll(km);
    float sv = __shfl_up(vr, 1);
    int si = __shfl_up(ir, 1);
    if (lane >= cnt) {
      vr = (lane == cnt) ? cv : sv;
      ir = (lane == cnt) ? cm : si;
    }
    th = __shfl(vr, KNN - 1);                      // refreshed 20th-best
    if (hit) hit &= __ballot(d > th);              // prune sub-threshold hits
  }
}

// bitonic seed sort (R5-R14): 64 (d, col=lane) pairs, d desc, ties ->
// lower col. Equals serial insertion into the empty list -> bit-identical.
__device__ __forceinline__ void seed_sort(float d, int lane,
                                          float& vr, int& ir, float& th) {
  float v = d; int ix = lane;
#pragma unroll
  for (int k = 2; k <= 64; k <<= 1) {
#pragma unroll
    for (int j = k >> 1; j > 0; j >>= 1) {
      float pv = __shfl_xor(v, j);
      int   pi = __shfl_xor(ix, j);
      bool lower = (lane & j) == 0;
      bool desc  = (lane & k) == 0;                // block direction
      bool mineBefore = (v > pv) || (v == pv && ix < pi);
      bool keep = (mineBefore == (lower == desc));
      v  = keep ? v  : pv;
      ix = keep ? ix : pi;
    }
  }
  vr = v; ir = ix; th = __shfl(v, KNN - 1);
}

// GEMM (8 rows x 8 cols per thread; lane==col within each 64-group) +
// register-direct selection. Verbatim R14 (passed, best k_knn at 384us).
template <bool SEED>
__device__ __forceinline__ void tile_work(const float* __restrict__ bp,
                                          const float* As,
                                          const float* xxb, int m0, int w, int lane,
                                          const float (&xnr)[8],
                                          float (&val)[8], int (&idx)[8],
                                          float (&thd)[8]) {
  float xm[8];
#pragma unroll
  for (int g = 0; g < 8; ++g) xm[g] = xxb[m0 + 64 * g + lane];

  const float* Aw = As + 8 * w;                    // rows 8w..8w+7, LDA=64
  const float* bc = bp + m0;                       // per-lane: col m0+lane

  v2f acc[8][4];                                   // [row][col-pair]
#pragma unroll
  for (int r = 0; r < 8; ++r)
#pragma unroll
    for (int gp = 0; gp < 4; ++gp) { acc[r][gp].x = 0.f; acc[r][gp].y = 0.f; }

#pragma unroll 2
  for (int c = 0; c < CH; ++c) {
    float4 A0 = *(const float4*)(Aw + c * 64);       // rows 8w..8w+3 (broadcast)
    float4 A1 = *(const float4*)(Aw + c * 64 + 4);   // rows 8w+4..8w+7
    const float* bcc = bc + (size_t)c * NPTS;
    v2f bb[4];
    bb[0].x = bcc[0];    bb[0].y = bcc[64];          // cols m0+{0,64}+lane
    bb[1].x = bcc[128];  bb[1].y = bcc[192];
    bb[2].x = bcc[256];  bb[2].y = bcc[320];
    bb[3].x = bcc[384];  bb[3].y = bcc[448];
    v2f a01; a01.x = A0.x; a01.y = A0.y;             // natural reg pairs from
    v2f a23; a23.x = A0.z; a23.y = A0.w;             // the b128 load
    v2f a45; a45.x = A1.x; a45.y = A1.y;
    v2f a67; a67.x = A1.z; a67.y = A1.w;
#pragma unroll
    for (int gp = 0; gp < 4; ++gp) {
      fma2pair(a01, bb[gp], acc[0][gp], acc[1][gp]);
      fma2pair(a23, bb[gp], acc[2][gp], acc[3][gp]);
      fma2pair(a45, bb[gp], acc[4][gp], acc[5][gp]);
      fma2pair(a67, bb[gp], acc[6][gp], acc[7][gp]);
    }
  }

#pragma unroll
  for (int r = 0; r < 8; ++r) {
#pragma unroll
    for (int gp = 0; gp < 4; ++gp) {
      float d0 = (2.f * acc[r][gp].x - xnr[r]) - xm[2 * gp];
      if (SEED && gp == 0) {
        seed_sort(d0, lane, val[r], idx[r], thd[r]);  // m0==0, g==0: col==lane
      } else {
        insert_group(d0, m0 + 128 * gp, lane, val[r], idx[r], thd[r]);
      }
      float d1 = (2.f * acc[r][gp].y - xnr[r]) - xm[2 * gp + 1];
      insert_group(d1, m0 + 128 * gp + 64, lane, val[r], idx[r], thd[r]);
    }
  }
}

// ---------------- K1: distance-GEMM + top-20 + FUSED output -----------------
// R14 chassis: 512 threads = 8 waves; wave w owns rows 8w..8w+7; 64 rows/
// block; grid 512 = 2 blocks/CU -> 4 waves/SIMD; B from L2 (XCD swizzle).
// NEW: k_out is fused into the epilogue. At main-loop end, lane l holds the
// l-th best index for each of the wave's 8 rows -> broadcast ids via shfl
// (k=0..19 ascending, same fmax order as the old k_out), gather P[id][o]
// (coalesced 256B lines, L2-resident), add Q, leaky, transpose through the
// dead As region (padded [64][65], conflict-free) and store coalesced.
// The idx global round-trip and the whole third kernel are deleted.
__launch_bounds__(512, 4)
__global__ void k_knn(const float* __restrict__ x, const float* __restrict__ xx,
                      const float* __restrict__ P, const float* __restrict__ Q,
                      float* __restrict__ out) {
  __shared__ float S[64 * 65];                     // As uses first 64*64
  float* As = S;                                   // [c][n], LDA=64
  int tid = threadIdx.x;
  int bid = blockIdx.x;
  int b = bid & 7, nb = bid >> 3;                  // XCD-swizzled decode
  int n0 = nb * 64;
  const float* xb = x + (size_t)b * CH * NPTS;
  const float* xxb = xx + b * NPTS;
  int lane = tid & 63;
  int w = tid >> 6;                                // 0..7

  // stage A-tile [c][n]: 4096 floats, 512 threads x 8 floats
  {
    int c = tid >> 3, n8 = (tid & 7) << 3;
    float4 v0 = *(const float4*)(xb + (size_t)c * NPTS + n0 + n8);
    float4 v1 = *(const float4*)(xb + (size_t)c * NPTS + n0 + n8 + 4);
    *(float4*)(As + c * 64 + n8) = v0;
    *(float4*)(As + c * 64 + n8 + 4) = v1;
  }

  float xnr[8];
#pragma unroll
  for (int r = 0; r < 8; ++r) xnr[r] = xxb[n0 + 8 * w + r];

  float val[8]; int idx[8]; float thd[8];
#pragma unroll
  for (int r = 0; r < 8; ++r) { val[r] = NEG_INF; idx[r] = 0; thd[r] = NEG_INF; }

  __syncthreads();                                 // As ready

  const float* bp = xb + lane;                     // per-lane B base

  // chunk 0: seeded selection
  tile_work<true>(bp, As, xxb, 0, w, lane, xnr, val, idx, thd);

#pragma unroll 1
  for (int mt = 1; mt < NPTS / 512; ++mt)
    tile_work<false>(bp, As, xxb, mt * 512, w, lane, xnr, val, idx, thd);

  // ---- fused output epilogue (replaces k_out; same op order -> bit-exact) --
  const float* Pb = P + (size_t)b * NPTS * 64;
  const float* Qb = Q + (size_t)b * NPTS * 64;
  __syncthreads();                                 // all As readers done
#pragma unroll
  for (int r = 0; r < 8; ++r) {
    int n = n0 + 8 * w + r;
    float mx = NEG_INF;
#pragma unroll
    for (int k = 0; k < KNN; ++k) {                // k ascending == old ip[k]
      int id = __shfl(idx[r], k);
      mx = fmaxf(mx, Pb[(size_t)id * 64 + lane]);  // coalesced 256B line
    }
    float z = mx + Qb[(size_t)n * 64 + lane];
    z = (z >= 0.f) ? z : NEG_SLOPE * z;
    S[lane * 65 + 8 * w + r] = z;                  // stride 65: conflict-free
  }
  __syncthreads();
  float* ob = out + (size_t)b * 64 * NPTS + n0;
#pragma unroll
  for (int r = 0; r < 8; ++r) {
    int o = 8 * w + r;
    ob[(size_t)o * NPTS + lane] = S[o * 65 + lane]; // coalesced 256B store
  }
}

extern "C" void kernel_launch(void* const* d_in, const int* in_sizes, int n_in,
                              void* d_out, int out_size, void* d_ws, size_t ws_size,
                              hipStream_t stream) {
  const float* x     = (const float*)d_in[0];
  const float* W     = (const float*)d_in[1];
  const float* gamma = (const float*)d_in[2];
  const float* beta  = (const float*)d_in[3];
  const float* rmean = (const float*)d_in[4];
  const float* rvar  = (const float*)d_in[5];
  float* out = (float*)d_out;

  float* xx = (float*)d_ws;                        // 32768 floats
  float* P  = xx + 32768;                          // 2097152 floats
  float* Q  = P + 2097152;                         // 2097152 floats

  k_pq<<<BATCH * NPTS / 16, 256, 0, stream>>>(x, W, gamma, beta, rmean, rvar,
                                              P, Q, xx);
  k_knn<<<BATCH * NPTS / 64, 512, 0, stream>>>(x, xx, P, Q, out);
}

// Round 17
// 449.844 us; speedup vs baseline: 1.8614x; 1.0628x over previous
//
#include <hip/hip_runtime.h>

#define NPTS 4096
#define CH 64
#define BATCH 8
#define KNN 20
#define NEG_SLOPE 0.2f
#define EPSV 1e-5f
#define NEG_INF (-3.4e38f)

typedef float v2f __attribute__((ext_vector_type(2)));

// ---------------- K2: P, Q, xx — tiled-LDS GEMM rewrite ----------------
// Old k_pq read x via wave-broadcast scalar loads (2M 64B-line reads for
// 4B used) and was 83us vs a ~5us roofline. New structure = k_knn's proven
// pattern: coalesced As stage + LDS W + broadcast-b128 A reads.
// 1024 blocks (4/CU, 40KB LDS), 256 thr = 4 waves; wave w owns rows
// 8w..8w+7 of a 32-row tile; lane = output channel o.
// Per-accumulator fma chains (c ascending), W scaling, +shift epilogue are
// verbatim from the old kernel -> P, Q, xx bit-identical.
__launch_bounds__(256, 4)
__global__ void k_pq(const float* __restrict__ x, const float* __restrict__ W,
                     const float* __restrict__ gamma, const float* __restrict__ beta,
                     const float* __restrict__ rmean, const float* __restrict__ rvar,
                     float* __restrict__ P, float* __restrict__ Q,
                     float* __restrict__ xx) {
  __shared__ float Ws1[CH * CH];   // [c][o], W1*inv
  __shared__ float Wsd[CH * CH];   // [c][o], (W2-W1)*inv
  __shared__ float As[CH * 32];    // [c][n], 32 rows per block
  int tid = threadIdx.x;
  int bid = blockIdx.x;
  int b = bid & 7, nb = bid >> 3;                  // XCD swizzle
  int n0 = nb * 32;
  const float* xb = x + (size_t)b * CH * NPTS;

  // stage scaled W (same arithmetic as before -> bit-identical)
  for (int i = tid; i < CH * CH; i += 256) {
    int o = i & 63, c = i >> 6;
    float s = gamma[o] * rsqrtf(rvar[o] + EPSV);
    float w1 = W[o * 128 + c], w2 = W[o * 128 + 64 + c];
    Ws1[c * 64 + o] = w1 * s;
    Wsd[c * 64 + o] = (w2 - w1) * s;
  }
  // stage As[c][n]: 2048 floats, coalesced float4
#pragma unroll
  for (int k = 0; k < 2; ++k) {
    int chunk = tid + 256 * k;                     // 0..511
    int c = chunk >> 3, cn = (chunk & 7) << 2;
    *(float4*)(As + c * 32 + cn) = *(const float4*)(xb + (size_t)c * NPTS + n0 + cn);
  }
  int o = tid & 63, w = tid >> 6;                  // lane = o; wave w
  float s = gamma[o] * rsqrtf(rvar[o] + EPSV);
  float shift = beta[o] - rmean[o] * s;
  __syncthreads();

  const float* Aw = As + 8 * w;                    // rows 8w..8w+7
  float p[8], q[8];
#pragma unroll
  for (int r = 0; r < 8; ++r) { p[r] = 0.f; q[r] = 0.f; }
#pragma unroll 4
  for (int c = 0; c < CH; ++c) {
    float4 A0 = *(const float4*)(Aw + c * 32);     // broadcast b128
    float4 A1 = *(const float4*)(Aw + c * 32 + 4);
    float w1v = Ws1[c * 64 + o];                   // per-lane, conflict-free
    float wdv = Wsd[c * 64 + o];
    float av[8] = {A0.x, A0.y, A0.z, A0.w, A1.x, A1.y, A1.z, A1.w};
#pragma unroll
    for (int r = 0; r < 8; ++r) {
      p[r] = fmaf(av[r], w1v, p[r]);               // same chain as old accp
      q[r] = fmaf(av[r], wdv, q[r]);               // same chain as old accq
    }
  }
  float* Pb = P + ((size_t)b * NPTS + n0) * 64;
  float* Qb = Q + ((size_t)b * NPTS + n0) * 64;
#pragma unroll
  for (int r = 0; r < 8; ++r) {
    int n = 8 * w + r;
    Pb[(size_t)n * 64 + o] = p[r];                 // coalesced 256B store
    Qb[(size_t)n * 64 + o] = q[r] + shift;
  }
  // xx for this block's 32 rows (wave 0, lanes 0..31): same fmaf(v,v) chain
  if (w == 0 && o < 32) {
    float accx = 0.f;
#pragma unroll 8
    for (int c = 0; c < CH; ++c) {
      float v = As[c * 32 + o];
      accx = fmaf(v, v, accx);
    }
    xx[(size_t)b * NPTS + n0 + o] = accx;
  }
}

// ---------------- K1 helpers (all R14/R16, passed) ----------------
__device__ __forceinline__ void fma2pair(v2f ap, v2f b, v2f& aclo, v2f& achi) {
  asm("v_pk_fma_f32 %0, %1, %2, %0 op_sel:[0,0,0] op_sel_hi:[0,1,1]"
      : "+v"(aclo) : "v"(ap), "v"(b));
  asm("v_pk_fma_f32 %0, %1, %2, %0 op_sel:[1,0,0] op_sel_hi:[1,1,1]"
      : "+v"(achi) : "v"(ap), "v"(b));
}

// ballot-gated serial insert with in-loop threshold tightening (R5-R16).
__device__ __forceinline__ void insert_group(float d, int mg, int lane,
                                             float& vr, int& ir, float& th) {
  unsigned long long hit = __ballot(d > th);
  while (hit) {
    int j = __builtin_ctzll(hit);
    hit &= hit - 1;
    float cv = __shfl(d, j);
    int cm = mg + j;
    unsigned long long km = __ballot(vr >= cv);    // existing equals stay above
    int cnt = __popcll(km);
    float sv = __shfl_up(vr, 1);
    int si = __shfl_up(ir, 1);
    if (lane >= cnt) {
      vr = (lane == cnt) ? cv : sv;
      ir = (lane == cnt) ? cm : si;
    }
    th = __shfl(vr, KNN - 1);                      // refreshed 20th-best
    if (hit) hit &= __ballot(d > th);              // prune sub-threshold hits
  }
}

// bitonic seed sort (R5-R16): 64 (d, col=lane) pairs, d desc, ties ->
// lower col. Equals serial insertion into the empty list -> bit-identical.
__device__ __forceinline__ void seed_sort(float d, int lane,
                                          float& vr, int& ir, float& th) {
  float v = d; int ix = lane;
#pragma unroll
  for (int k = 2; k <= 64; k <<= 1) {
#pragma unroll
    for (int j = k >> 1; j > 0; j >>= 1) {
      float pv = __shfl_xor(v, j);
      int   pi = __shfl_xor(ix, j);
      bool lower = (lane & j) == 0;
      bool desc  = (lane & k) == 0;                // block direction
      bool mineBefore = (v > pv) || (v == pv && ix < pi);
      bool keep = (mineBefore == (lower == desc));
      v  = keep ? v  : pv;
      ix = keep ? ix : pi;
    }
  }
  vr = v; ir = ix; th = __shfl(v, KNN - 1);
}

// GEMM (8 rows x 8 cols per thread) + register-direct selection.
// Verbatim R14/R16 (passed).
template <bool SEED>
__device__ __forceinline__ void tile_work(const float* __restrict__ bp,
                                          const float* As,
                                          const float* xxb, int m0, int w, int lane,
                                          const float (&xnr)[8],
                                          float (&val)[8], int (&idx)[8],
                                          float (&thd)[8]) {
  float xm[8];
#pragma unroll
  for (int g = 0; g < 8; ++g) xm[g] = xxb[m0 + 64 * g + lane];

  const float* Aw = As + 8 * w;                    // rows 8w..8w+7, LDA=64
  const float* bc = bp + m0;                       // per-lane: col m0+lane

  v2f acc[8][4];                                   // [row][col-pair]
#pragma unroll
  for (int r = 0; r < 8; ++r)
#pragma unroll
    for (int gp = 0; gp < 4; ++gp) { acc[r][gp].x = 0.f; acc[r][gp].y = 0.f; }

#pragma unroll 2
  for (int c = 0; c < CH; ++c) {
    float4 A0 = *(const float4*)(Aw + c * 64);       // rows 8w..8w+3 (broadcast)
    float4 A1 = *(const float4*)(Aw + c * 64 + 4);   // rows 8w+4..8w+7
    const float* bcc = bc + (size_t)c * NPTS;
    v2f bb[4];
    bb[0].x = bcc[0];    bb[0].y = bcc[64];          // cols m0+{0,64}+lane
    bb[1].x = bcc[128];  bb[1].y = bcc[192];
    bb[2].x = bcc[256];  bb[2].y = bcc[320];
    bb[3].x = bcc[384];  bb[3].y = bcc[448];
    v2f a01; a01.x = A0.x; a01.y = A0.y;
    v2f a23; a23.x = A0.z; a23.y = A0.w;
    v2f a45; a45.x = A1.x; a45.y = A1.y;
    v2f a67; a67.x = A1.z; a67.y = A1.w;
#pragma unroll
    for (int gp = 0; gp < 4; ++gp) {
      fma2pair(a01, bb[gp], acc[0][gp], acc[1][gp]);
      fma2pair(a23, bb[gp], acc[2][gp], acc[3][gp]);
      fma2pair(a45, bb[gp], acc[4][gp], acc[5][gp]);
      fma2pair(a67, bb[gp], acc[6][gp], acc[7][gp]);
    }
  }

#pragma unroll
  for (int r = 0; r < 8; ++r) {
#pragma unroll
    for (int gp = 0; gp < 4; ++gp) {
      float d0 = (2.f * acc[r][gp].x - xnr[r]) - xm[2 * gp];
      if (SEED && gp == 0) {
        seed_sort(d0, lane, val[r], idx[r], thd[r]);  // m0==0, g==0: col==lane
      } else {
        insert_group(d0, m0 + 128 * gp, lane, val[r], idx[r], thd[r]);
      }
      float d1 = (2.f * acc[r][gp].y - xnr[r]) - xm[2 * gp + 1];
      insert_group(d1, m0 + 128 * gp + 64, lane, val[r], idx[r], thd[r]);
    }
  }
}

// ---------------- K1: distance-GEMM + top-20 + fused output (R16) -----------
__launch_bounds__(512, 4)
__global__ void k_knn(const float* __restrict__ x, const float* __restrict__ xx,
                      const float* __restrict__ P, const float* __restrict__ Q,
                      float* __restrict__ out) {
  __shared__ float S[64 * 65];                     // As uses first 64*64
  float* As = S;                                   // [c][n], LDA=64
  int tid = threadIdx.x;
  int bid = blockIdx.x;
  int b = bid & 7, nb = bid >> 3;                  // XCD-swizzled decode
  int n0 = nb * 64;
  const float* xb = x + (size_t)b * CH * NPTS;
  const float* xxb = xx + b * NPTS;
  int lane = tid & 63;
  int w = tid >> 6;                                // 0..7

  // stage A-tile [c][n]: 4096 floats, 512 threads x 8 floats
  {
    int c = tid >> 3, n8 = (tid & 7) << 3;
    float4 v0 = *(const float4*)(xb + (size_t)c * NPTS + n0 + n8);
    float4 v1 = *(const float4*)(xb + (size_t)c * NPTS + n0 + n8 + 4);
    *(float4*)(As + c * 64 + n8) = v0;
    *(float4*)(As + c * 64 + n8 + 4) = v1;
  }

  float xnr[8];
#pragma unroll
  for (int r = 0; r < 8; ++r) xnr[r] = xxb[n0 + 8 * w + r];

  float val[8]; int idx[8]; float thd[8];
#pragma unroll
  for (int r = 0; r < 8; ++r) { val[r] = NEG_INF; idx[r] = 0; thd[r] = NEG_INF; }

  __syncthreads();                                 // As ready

  const float* bp = xb + lane;                     // per-lane B base

  // chunk 0: seeded selection
  tile_work<true>(bp, As, xxb, 0, w, lane, xnr, val, idx, thd);

#pragma unroll 1
  for (int mt = 1; mt < NPTS / 512; ++mt)
    tile_work<false>(bp, As, xxb, mt * 512, w, lane, xnr, val, idx, thd);

  // ---- fused output epilogue (same op order as old k_out -> bit-exact) ----
  const float* Pb = P + (size_t)b * NPTS * 64;
  const float* Qb = Q + (size_t)b * NPTS * 64;
  __syncthreads();                                 // all As readers done
#pragma unroll
  for (int r = 0; r < 8; ++r) {
    int n = n0 + 8 * w + r;
    float mx = NEG_INF;
#pragma unroll
    for (int k = 0; k < KNN; ++k) {                // k ascending == old ip[k]
      int id = __shfl(idx[r], k);
      mx = fmaxf(mx, Pb[(size_t)id * 64 + lane]);  // coalesced 256B line
    }
    float z = mx + Qb[(size_t)n * 64 + lane];
    z = (z >= 0.f) ? z : NEG_SLOPE * z;
    S[lane * 65 + 8 * w + r] = z;                  // stride 65: conflict-free
  }
  __syncthreads();
  float* ob = out + (size_t)b * 64 * NPTS + n0;
#pragma unroll
  for (int r = 0; r < 8; ++r) {
    int o = 8 * w + r;
    ob[(size_t)o * NPTS + lane] = S[o * 65 + lane]; // coalesced 256B store
  }
}

extern "C" void kernel_launch(void* const* d_in, const int* in_sizes, int n_in,
                              void* d_out, int out_size, void* d_ws, size_t ws_size,
                              hipStream_t stream) {
  const float* x     = (const float*)d_in[0];
  const float* W     = (const float*)d_in[1];
  const float* gamma = (const float*)d_in[2];
  const float* beta  = (const float*)d_in[3];
  const float* rmean = (const float*)d_in[4];
  const float* rvar  = (const float*)d_in[5];
  float* out = (float*)d_out;

  float* xx = (float*)d_ws;                        // 32768 floats
  float* P  = xx + 32768;                          // 2097152 floats
  float* Q  = P + 2097152;                         // 2097152 floats

  k_pq<<<BATCH * NPTS / 32, 256, 0, stream>>>(x, W, gamma, beta, rmean, rvar,
                                              P, Q, xx);
  k_knn<<<BATCH * NPTS / 64, 512, 0, stream>>>(x, xx, P, Q, out);
}

// Round 18
// 439.986 us; speedup vs baseline: 1.9031x; 1.0224x over previous
//
#include <hip/hip_runtime.h>

#define NPTS 4096
#define CH 64
#define BATCH 8
#define KNN 20
#define NEG_SLOPE 0.2f
#define EPSV 1e-5f
#define NEG_INF (-3.4e38f)

typedef float v2f __attribute__((ext_vector_type(2)));

// forced v_pk_fma_f32 (R14, passed): aclo += (ap.lo,ap.lo)*b;
// achi += (ap.hi,ap.hi)*b. Each lane is an IEEE fma -> bit-identical chains.
__device__ __forceinline__ void fma2pair(v2f ap, v2f b, v2f& aclo, v2f& achi) {
  asm("v_pk_fma_f32 %0, %1, %2, %0 op_sel:[0,0,0] op_sel_hi:[0,1,1]"
      : "+v"(aclo) : "v"(ap), "v"(b));
  asm("v_pk_fma_f32 %0, %1, %2, %0 op_sel:[1,0,0] op_sel_hi:[1,1,1]"
      : "+v"(achi) : "v"(ap), "v"(b));
}

// ---------------- K2: P, Q, xx — R17 structure + three mechanical fixes -----
// 1) W loads COALESCED (c = lane; R17 had o = lane -> 64 lines/wave-load).
// 2) s/shift computed ONCE per o into LDS (64 rsqrtf/block, was 4096).
//    Same input bits -> same rsqrtf bits -> W scaling bit-identical.
// 3) compute loop uses fma2pair: (p[r],q[r]) pair vs (w1,wd) pair; each
//    lane is the same IEEE fma chain (c ascending) as before.
// LDS Ws layout [c][65]: write lane=c stride-65 -> bank (c+o)%32, 2-way
// (free, m136); read lane=o -> bank (c+o)%32, 2-way (free).
__launch_bounds__(256, 4)
__global__ void k_pq(const float* __restrict__ x, const float* __restrict__ W,
                     const float* __restrict__ gamma, const float* __restrict__ beta,
                     const float* __restrict__ rmean, const float* __restrict__ rvar,
                     float* __restrict__ P, float* __restrict__ Q,
                     float* __restrict__ xx) {
  __shared__ float Ws1[CH * 65];   // [c][o] padded, W1*inv
  __shared__ float Wsd[CH * 65];   // [c][o] padded, (W2-W1)*inv
  __shared__ float As[CH * 32];    // [c][n], 32 rows per block
  __shared__ float s_sh[64], shift_sh[64];
  int tid = threadIdx.x;
  int bid = blockIdx.x;
  int b = bid & 7, nb = bid >> 3;                  // XCD swizzle
  int n0 = nb * 32;
  const float* xb = x + (size_t)b * CH * NPTS;

  // s, shift once per o (64 rsqrtf total; same bits as per-element compute)
  if (tid < 64) {
    float s = gamma[tid] * rsqrtf(rvar[tid] + EPSV);
    s_sh[tid] = s;
    shift_sh[tid] = beta[tid] - rmean[tid] * s;
  }
  // stage As[c][n]: 2048 floats, coalesced float4
#pragma unroll
  for (int k = 0; k < 2; ++k) {
    int chunk = tid + 256 * k;                     // 0..511
    int c = chunk >> 3, cn = (chunk & 7) << 2;
    *(float4*)(As + c * 32 + cn) = *(const float4*)(xb + (size_t)c * NPTS + n0 + cn);
  }
  __syncthreads();                                 // s_sh ready for W scaling

  // stage scaled W: i -> o = i>>6, c = i&63 (lane = c -> coalesced reads).
  // Same arithmetic as R17 (w1*s, (w2-w1)*s) -> bit-identical values.
  for (int i = tid; i < CH * CH; i += 256) {
    int o = i >> 6, c = i & 63;
    float s = s_sh[o];
    float w1 = W[o * 128 + c], w2 = W[o * 128 + 64 + c];
    Ws1[c * 65 + o] = w1 * s;
    Wsd[c * 65 + o] = (w2 - w1) * s;
  }
  int o = tid & 63, w = tid >> 6;                  // lane = o; wave w
  __syncthreads();

  const float* Aw = As + 8 * w;                    // rows 8w..8w+7
  v2f pq[8];                                       // (p[r], q[r]) pairs
#pragma unroll
  for (int r = 0; r < 8; ++r) { pq[r].x = 0.f; pq[r].y = 0.f; }
#pragma unroll 4
  for (int c = 0; c < CH; ++c) {
    float4 A0 = *(const float4*)(Aw + c * 32);     // broadcast b128
    float4 A1 = *(const float4*)(Aw + c * 32 + 4);
    v2f wv; wv.x = Ws1[c * 65 + o]; wv.y = Wsd[c * 65 + o];
    v2f a01; a01.x = A0.x; a01.y = A0.y;
    v2f a23; a23.x = A0.z; a23.y = A0.w;
    v2f a45; a45.x = A1.x; a45.y = A1.y;
    v2f a67; a67.x = A1.z; a67.y = A1.w;
    fma2pair(a01, wv, pq[0], pq[1]);               // p[r]+=a*w1, q[r]+=a*wd
    fma2pair(a23, wv, pq[2], pq[3]);
    fma2pair(a45, wv, pq[4], pq[5]);
    fma2pair(a67, wv, pq[6], pq[7]);
  }
  float shift = shift_sh[o];
  float* Pb = P + ((size_t)b * NPTS + n0) * 64;
  float* Qb = Q + ((size_t)b * NPTS + n0) * 64;
#pragma unroll
  for (int r = 0; r < 8; ++r) {
    int n = 8 * w + r;
    Pb[(size_t)n * 64 + o] = pq[r].x;              // coalesced 256B store
    Qb[(size_t)n * 64 + o] = pq[r].y + shift;
  }
  // xx for this block's 32 rows (wave 0, lanes 0..31): same fmaf(v,v) chain
  if (w == 0 && o < 32) {
    float accx = 0.f;
#pragma unroll 8
    for (int c = 0; c < CH; ++c) {
      float v = As[c * 32 + o];
      accx = fmaf(v, v, accx);
    }
    xx[(size_t)b * NPTS + n0 + o] = accx;
  }
}

// ---------------- K1 helpers (all R14/R16, passed) ----------------
// ballot-gated serial insert with in-loop threshold tightening (R5-R17).
__device__ __forceinline__ void insert_group(float d, int mg, int lane,
                                             float& vr, int& ir, float& th) {
  unsigned long long hit = __ballot(d > th);
  while (hit) {
    int j = __builtin_ctzll(hit);
    hit &= hit - 1;
    float cv = __shfl(d, j);
    int cm = mg + j;
    unsigned long long km = __ballot(vr >= cv);    // existing equals stay above
    int cnt = __popcll(km);
    float sv = __shfl_up(vr, 1);
    int si = __shfl_up(ir, 1);
    if (lane >= cnt) {
      vr = (lane == cnt) ? cv : sv;
      ir = (lane == cnt) ? cm : si;
    }
    th = __shfl(vr, KNN - 1);                      // refreshed 20th-best
    if (hit) hit &= __ballot(d > th);              // prune sub-threshold hits
  }
}

// bitonic seed sort (R5-R17): 64 (d, col=lane) pairs, d desc, ties ->
// lower col. Equals serial insertion into the empty list -> bit-identical.
__device__ __forceinline__ void seed_sort(float d, int lane,
                                          float& vr, int& ir, float& th) {
  float v = d; int ix = lane;
#pragma unroll
  for (int k = 2; k <= 64; k <<= 1) {
#pragma unroll
    for (int j = k >> 1; j > 0; j >>= 1) {
      float pv = __shfl_xor(v, j);
      int   pi = __shfl_xor(ix, j);
      bool lower = (lane & j) == 0;
      bool desc  = (lane & k) == 0;                // block direction
      bool mineBefore = (v > pv) || (v == pv && ix < pi);
      bool keep = (mineBefore == (lower == desc));
      v  = keep ? v  : pv;
      ix = keep ? ix : pi;
    }
  }
  vr = v; ir = ix; th = __shfl(v, KNN - 1);
}

// GEMM (8 rows x 8 cols per thread) + register-direct selection.
// Verbatim R14/R16/R17 (passed).
template <bool SEED>
__device__ __forceinline__ void tile_work(const float* __restrict__ bp,
                                          const float* As,
                                          const float* xxb, int m0, int w, int lane,
                                          const float (&xnr)[8],
                                          float (&val)[8], int (&idx)[8],
                                          float (&thd)[8]) {
  float xm[8];
#pragma unroll
  for (int g = 0; g < 8; ++g) xm[g] = xxb[m0 + 64 * g + lane];

  const float* Aw = As + 8 * w;                    // rows 8w..8w+7, LDA=64
  const float* bc = bp + m0;                       // per-lane: col m0+lane

  v2f acc[8][4];                                   // [row][col-pair]
#pragma unroll
  for (int r = 0; r < 8; ++r)
#pragma unroll
    for (int gp = 0; gp < 4; ++gp) { acc[r][gp].x = 0.f; acc[r][gp].y = 0.f; }

#pragma unroll 2
  for (int c = 0; c < CH; ++c) {
    float4 A0 = *(const float4*)(Aw + c * 64);       // rows 8w..8w+3 (broadcast)
    float4 A1 = *(const float4*)(Aw + c * 64 + 4);   // rows 8w+4..8w+7
    const float* bcc = bc + (size_t)c * NPTS;
    v2f bb[4];
    bb[0].x = bcc[0];    bb[0].y = bcc[64];          // cols m0+{0,64}+lane
    bb[1].x = bcc[128];  bb[1].y = bcc[192];
    bb[2].x = bcc[256];  bb[2].y = bcc[320];
    bb[3].x = bcc[384];  bb[3].y = bcc[448];
    v2f a01; a01.x = A0.x; a01.y = A0.y;
    v2f a23; a23.x = A0.z; a23.y = A0.w;
    v2f a45; a45.x = A1.x; a45.y = A1.y;
    v2f a67; a67.x = A1.z; a67.y = A1.w;
#pragma unroll
    for (int gp = 0; gp < 4; ++gp) {
      fma2pair(a01, bb[gp], acc[0][gp], acc[1][gp]);
      fma2pair(a23, bb[gp], acc[2][gp], acc[3][gp]);
      fma2pair(a45, bb[gp], acc[4][gp], acc[5][gp]);
      fma2pair(a67, bb[gp], acc[6][gp], acc[7][gp]);
    }
  }

#pragma unroll
  for (int r = 0; r < 8; ++r) {
#pragma unroll
    for (int gp = 0; gp < 4; ++gp) {
      float d0 = (2.f * acc[r][gp].x - xnr[r]) - xm[2 * gp];
      if (SEED && gp == 0) {
        seed_sort(d0, lane, val[r], idx[r], thd[r]);  // m0==0, g==0: col==lane
      } else {
        insert_group(d0, m0 + 128 * gp, lane, val[r], idx[r], thd[r]);
      }
      float d1 = (2.f * acc[r][gp].y - xnr[r]) - xm[2 * gp + 1];
      insert_group(d1, m0 + 128 * gp + 64, lane, val[r], idx[r], thd[r]);
    }
  }
}

// ---------------- K1: distance-GEMM + top-20 + fused output (R16/R17) -------
__launch_bounds__(512, 4)
__global__ void k_knn(const float* __restrict__ x, const float* __restrict__ xx,
                      const float* __restrict__ P, const float* __restrict__ Q,
                      float* __restrict__ out) {
  __shared__ float S[64 * 65];                     // As uses first 64*64
  float* As = S;                                   // [c][n], LDA=64
  int tid = threadIdx.x;
  int bid = blockIdx.x;
  int b = bid & 7, nb = bid >> 3;                  // XCD-swizzled decode
  int n0 = nb * 64;
  const float* xb = x + (size_t)b * CH * NPTS;
  const float* xxb = xx + b * NPTS;
  int lane = tid & 63;
  int w = tid >> 6;                                // 0..7

  // stage A-tile [c][n]: 4096 floats, 512 threads x 8 floats
  {
    int c = tid >> 3, n8 = (tid & 7) << 3;
    float4 v0 = *(const float4*)(xb + (size_t)c * NPTS + n0 + n8);
    float4 v1 = *(const float4*)(xb + (size_t)c * NPTS + n0 + n8 + 4);
    *(float4*)(As + c * 64 + n8) = v0;
    *(float4*)(As + c * 64 + n8 + 4) = v1;
  }

  float xnr[8];
#pragma unroll
  for (int r = 0; r < 8; ++r) xnr[r] = xxb[n0 + 8 * w + r];

  float val[8]; int idx[8]; float thd[8];
#pragma unroll
  for (int r = 0; r < 8; ++r) { val[r] = NEG_INF; idx[r] = 0; thd[r] = NEG_INF; }

  __syncthreads();                                 // As ready

  const float* bp = xb + lane;                     // per-lane B base

  // chunk 0: seeded selection
  tile_work<true>(bp, As, xxb, 0, w, lane, xnr, val, idx, thd);

#pragma unroll 1
  for (int mt = 1; mt < NPTS / 512; ++mt)
    tile_work<false>(bp, As, xxb, mt * 512, w, lane, xnr, val, idx, thd);

  // ---- fused output epilogue (same op order as old k_out -> bit-exact) ----
  const float* Pb = P + (size_t)b * NPTS * 64;
  const float* Qb = Q + (size_t)b * NPTS * 64;
  __syncthreads();                                 // all As readers done
#pragma unroll
  for (int r = 0; r < 8; ++r) {
    int n = n0 + 8 * w + r;
    float mx = NEG_INF;
#pragma unroll
    for (int k = 0; k < KNN; ++k) {                // k ascending == old ip[k]
      int id = __shfl(idx[r], k);
      mx = fmaxf(mx, Pb[(size_t)id * 64 + lane]);  // coalesced 256B line
    }
    float z = mx + Qb[(size_t)n * 64 + lane];
    z = (z >= 0.f) ? z : NEG_SLOPE * z;
    S[lane * 65 + 8 * w + r] = z;                  // stride 65: conflict-free
  }
  __syncthreads();
  float* ob = out + (size_t)b * 64 * NPTS + n0;
#pragma unroll
  for (int r = 0; r < 8; ++r) {
    int o = 8 * w + r;
    ob[(size_t)o * NPTS + lane] = S[o * 65 + lane]; // coalesced 256B store
  }
}

extern "C" void kernel_launch(void* const* d_in, const int* in_sizes, int n_in,
                              void* d_out, int out_size, void* d_ws, size_t ws_size,
                              hipStream_t stream) {
  const float* x     = (const float*)d_in[0];
  const float* W     = (const float*)d_in[1];
  const float* gamma = (const float*)d_in[2];
  const float* beta  = (const float*)d_in[3];
  const float* rmean = (const float*)d_in[4];
  const float* rvar  = (const float*)d_in[5];
  float* out = (float*)d_out;

  float* xx = (float*)d_ws;                        // 32768 floats
  float* P  = xx + 32768;                          // 2097152 floats
  float* Q  = P + 2097152;                         // 2097152 floats

  k_pq<<<BATCH * NPTS / 32, 256, 0, stream>>>(x, W, gamma, beta, rmean, rvar,
                                              P, Q, xx);
  k_knn<<<BATCH * NPTS / 64, 512, 0, stream>>>(x, xx, P, Q, out);
}